// Round 16
// baseline (91.659 us; speedup 1.0000x reference)
//
#include <hip/hip_runtime.h>
#include <cmath>

#define TABLE_NUM 16
#define T_SIZE    4096
#define Z_DIM     512
#define IMG       256
#define D_TAB     (TABLE_NUM * T_SIZE * 2)       // 131072
#define BATCH     8
#define HID       64
#define N_PIX     (IMG * IMG)                    // 65536
#define PRIME_Y   2654435761u
#define KCHUNK    4
#define KLEN      (Z_DIM / KCHUNK)               // 128
#define NG4       (D_TAB / 4)                    // 32768 float4 col-groups

typedef _Float16 v8h  __attribute__((ext_vector_type(8)));
typedef _Float16 v2h  __attribute__((ext_vector_type(2)));
typedef float    v4f  __attribute__((ext_vector_type(4)));

struct ResArr { float r[TABLE_NUM]; };

// per-level corner-window caps for a 16x16-pixel block (R8-proven)
__device__ constexpr int WCAP[16]  = {3,4,4,4,5,5,5,6,7,8,9,10,11,13,15,18};
__device__ constexpr int CBASE[16] = {0,9,25,41,57,82,107,132,168,217,281,362,462,583,752,977};
#define CTOT 1301

// ---------------------------------------------------------------------------
// Kernel 0: weight transpose/cast + z transpose — grid-stride, 16 blocks.
// ---------------------------------------------------------------------------
__global__ void prep_weights(const float* __restrict__ w1, const float* __restrict__ w2,
                             const float* __restrict__ w3, const float* __restrict__ z,
                             _Float16* __restrict__ w1T, _Float16* __restrict__ w2T,
                             _Float16* __restrict__ w3T, float* __restrict__ zT)
{
    const int t0  = blockIdx.x * 256 + threadIdx.x;
    const int stp = gridDim.x * 256;
    for (int i = t0; i < HID * 32; i += stp) {
        int n = i >> 5, k = i & 31;
        w1T[i] = (_Float16)w1[k * HID + n];
    }
    for (int i = t0; i < HID * HID; i += stp) {
        int n = i >> 6, k = i & 63;
        w2T[i] = (_Float16)w2[k * HID + n];
    }
    for (int i = t0; i < 16 * HID; i += stp) {
        int n = i >> 6, k = i & 63;
        w3T[i] = (_Float16)(n < 3 ? w3[k * 3 + n] : 0.f);
    }
    for (int i = t0; i < Z_DIM * BATCH; i += stp) {
        int k = i >> 3, b = i & 7;
        zT[i] = z[b * Z_DIM + k];
    }
}

// ---------------------------------------------------------------------------
// Kernel 1a: k-split partial GEMM (unchanged from R7; ~44 us @ 6.4 TB/s —
// within ~4% of the 268 MB stream floor).
// ---------------------------------------------------------------------------
__global__ __launch_bounds__(256) void gen_partial(
    const float* __restrict__ zT, const float* __restrict__ w,
    float* __restrict__ part)
{
    const int c  = blockIdx.x >> 7;
    const int g  = (blockIdx.x & 127) * 256 + threadIdx.x;
    const int k0 = c * KLEN;
    const float4* wp = reinterpret_cast<const float4*>(w) + g;

    float4 acc[BATCH];
#pragma unroll
    for (int b = 0; b < BATCH; ++b) acc[b] = make_float4(0.f, 0.f, 0.f, 0.f);

#pragma unroll 8
    for (int kk = 0; kk < KLEN; ++kk) {
        const int k = k0 + kk;
        float4 wv = wp[(size_t)k * NG4];
        const float* zr = zT + k * BATCH;
#pragma unroll
        for (int b = 0; b < BATCH; ++b) {
            float zv = zr[b];
            acc[b].x = fmaf(zv, wv.x, acc[b].x);
            acc[b].y = fmaf(zv, wv.y, acc[b].y);
            acc[b].z = fmaf(zv, wv.z, acc[b].z);
            acc[b].w = fmaf(zv, wv.w, acc[b].w);
        }
    }

    float4* pp = reinterpret_cast<float4*>(part);
#pragma unroll
    for (int b = 0; b < BATCH; ++b)
        pp[((size_t)(c * BATCH + b) << 15) + g] = acc[b];
}

// ---------------------------------------------------------------------------
// Kernel 1b: fold partials + bias (unchanged from R7; ~3.5 us).
// ---------------------------------------------------------------------------
__global__ __launch_bounds__(256) void gen_reduce(
    const float* __restrict__ part, const float* __restrict__ bt,
    float* __restrict__ tabs)
{
    const int i = blockIdx.x * 256 + threadIdx.x;
    const int b = i >> 15, g = i & (NG4 - 1);
    const float4* pp = reinterpret_cast<const float4*>(part);

    float4 s = pp[((size_t)b << 15) + g];
#pragma unroll
    for (int c = 1; c < KCHUNK; ++c) {
        float4 p = pp[((size_t)(c * BATCH + b) << 15) + g];
        s.x += p.x; s.y += p.y; s.z += p.z; s.w += p.w;
    }
    float4 bv = reinterpret_cast<const float4*>(bt)[g];
    s.x += bv.x; s.y += bv.y; s.z += bv.z; s.w += bv.w;
    reinterpret_cast<float4*>(tabs)[((size_t)b << 15) + g] = s;
}

// ---------------------------------------------------------------------------
// Kernel 2: R8's corner-pyramid staging (TA-free gathers; proven correct) +
// R15's fused low-liveness MLP (proven correct). NO min-waves launch_bounds
// (convicted miscompile trigger, R11/R14). LDS 47.3 KB -> 3 blocks/CU ->
// 3 waves/SIMD (+50% latency hiding vs R8's 2), VGPR naturally ~110-130.
// ---------------------------------------------------------------------------
__global__ __launch_bounds__(256) void hash_mlp(
    const float* __restrict__ tabs,
    const _Float16* __restrict__ w1T, const _Float16* __restrict__ w2T,
    const _Float16* __restrict__ w3T,
    const float* __restrict__ b1, const float* __restrict__ b2,
    const float* __restrict__ b3,
    float* __restrict__ out, ResArr res)
{
    __shared__ _Float16 mbuf[4][64][72];       // 36.9 KB per-wave MFMA staging
    __shared__ float2   cstage[CTOT];          // 10.4 KB corner pyramid

    const int tid  = threadIdx.x;
    const int wid  = tid >> 6;
    const int lane = tid & 63;
    const int b    = blockIdx.x & 7;          // batch == XCD (round-robin)
    const int tile = blockIdx.x >> 3;         // 16x16 pixel block
    const int i0b  = (tile >> 4) * 16;
    const int j0b  = (tile & 15) * 16;
    const int i0   = i0b + wid * 4;

    const int di = lane >> 4, dj = lane & 15;
    const float cxp = ((float)(i0 + di) + 0.5f) * (1.0f / IMG);
    const float cyp = ((float)(j0b + dj) + 0.5f) * (1.0f / IMG);
    const float2* tb2 = reinterpret_cast<const float2*>(tabs + (size_t)b * D_TAB);

    const float cx_lo = ((float)i0b + 0.5f) * (1.0f / IMG);
    const float cy_lo = ((float)j0b + 0.5f) * (1.0f / IMG);

    // ---- stage the full corner pyramid (one barrier; R8-verbatim) ----
#pragma unroll
    for (int l = 0; l < TABLE_NUM; ++l) {
        const float r  = res.r[l];
        const int   xs = (int)floorf(cx_lo * r);
        const int   ys = (int)floorf(cy_lo * r);
        const float2* tl = tb2 + l * T_SIZE;
        const int W = WCAP[l], CNT = WCAP[l] * WCAP[l];
        for (int e = tid; e < CNT; e += 256) {
            int yy = e / W, xx = e - yy * W;               // compile-time W
            unsigned idx = ((unsigned)(xs + xx) ^
                            ((unsigned)(ys + yy) * PRIME_Y)) & (T_SIZE - 1);
            cstage[CBASE[l] + e] = tl[idx];
        }
    }
    __syncthreads();

    // ---- consume: bilinear from LDS, f16 pairs into mbuf (R8-verbatim) ----
#pragma unroll
    for (int l = 0; l < TABLE_NUM; ++l) {
        const float r   = res.r[l];
        const float xsf = floorf(cx_lo * r);
        const float ysf = floorf(cy_lo * r);
        float px = cxp * r, py = cyp * r;
        float fx0 = floorf(px), fy0 = floorf(py);
        float fx = px - fx0, fy = py - fy0;
        int xi = (int)(fx0 - xsf), yi = (int)(fy0 - ysf);
        const float2* cb = cstage + CBASE[l];
        const int W = WCAP[l];
        float2 f00 = cb[yi * W + xi];
        float2 f10 = cb[yi * W + xi + 1];
        float2 f01 = cb[(yi + 1) * W + xi];
        float2 f11 = cb[(yi + 1) * W + xi + 1];
        float w00 = (1.f - fx) * (1.f - fy);
        float w10 = fx * (1.f - fy);
        float w01 = (1.f - fx) * fy;
        float w11 = fx * fy;
        float e0 = f00.x * w00 + f10.x * w10 + f01.x * w01 + f11.x * w11;
        float e1 = f00.y * w00 + f10.y * w10 + f01.y * w01 + f11.y * w11;
        v2h p; p.x = (_Float16)e0; p.y = (_Float16)e1;
        *reinterpret_cast<v2h*>(&mbuf[wid][lane][2 * l]) = p;
    }

    const int arow = lane & 15;        // A row / B col / C col
    const int kgrp = lane >> 4;        // k-group

    // ---- layer 1: 32 -> 64; per-nt fused relu+write (R15-verbatim) ----
    v8h a1[4];
#pragma unroll
    for (int mt = 0; mt < 4; ++mt)
        a1[mt] = *reinterpret_cast<const v8h*>(&mbuf[wid][mt * 16 + arow][kgrp * 8]);

#pragma unroll
    for (int nt = 0; nt < 4; ++nt) {
        v8h bf1 = *reinterpret_cast<const v8h*>(&w1T[(nt * 16 + arow) * 32 + kgrp * 8]);
        const float bias = b1[nt * 16 + arow];
#pragma unroll
        for (int mt = 0; mt < 4; ++mt) {
            v4f c = {0.f, 0.f, 0.f, 0.f};
            c = __builtin_amdgcn_mfma_f32_16x16x32_f16(a1[mt], bf1, c, 0, 0, 0);
#pragma unroll
            for (int e = 0; e < 4; ++e)
                mbuf[wid][mt * 16 + kgrp * 4 + e][nt * 16 + arow] =
                    (_Float16)fmaxf(c[e] + bias, 0.f);
        }
    }

    // ---- layer 2: 64 -> 64; a2 fully in regs first (WAR-safe) ----
    v8h a2[4][2];
#pragma unroll
    for (int mt = 0; mt < 4; ++mt) {
        a2[mt][0] = *reinterpret_cast<const v8h*>(&mbuf[wid][mt * 16 + arow][kgrp * 8]);
        a2[mt][1] = *reinterpret_cast<const v8h*>(&mbuf[wid][mt * 16 + arow][32 + kgrp * 8]);
    }
#pragma unroll
    for (int nt = 0; nt < 4; ++nt) {
        v8h bf2a = *reinterpret_cast<const v8h*>(&w2T[(nt * 16 + arow) * 64 + kgrp * 8]);
        v8h bf2b = *reinterpret_cast<const v8h*>(&w2T[(nt * 16 + arow) * 64 + 32 + kgrp * 8]);
        const float bias = b2[nt * 16 + arow];
#pragma unroll
        for (int mt = 0; mt < 4; ++mt) {
            v4f c = {0.f, 0.f, 0.f, 0.f};
            c = __builtin_amdgcn_mfma_f32_16x16x32_f16(a2[mt][0], bf2a, c, 0, 0, 0);
            c = __builtin_amdgcn_mfma_f32_16x16x32_f16(a2[mt][1], bf2b, c, 0, 0, 0);
#pragma unroll
            for (int e = 0; e < 4; ++e)
                mbuf[wid][mt * 16 + kgrp * 4 + e][nt * 16 + arow] =
                    (_Float16)fmaxf(c[e] + bias, 0.f);
        }
    }

    // ---- layer 3: 64 -> 3 (padded 16), tanh, coalesced row stores ----
    const float bias3 = (arow < 3) ? b3[arow] : 0.f;
#pragma unroll
    for (int mt = 0; mt < 4; ++mt) {
        v8h bf3a = *reinterpret_cast<const v8h*>(&w3T[arow * 64 + kgrp * 8]);
        v8h bf3b = *reinterpret_cast<const v8h*>(&w3T[arow * 64 + 32 + kgrp * 8]);
        v8h a0  = *reinterpret_cast<const v8h*>(&mbuf[wid][mt * 16 + arow][kgrp * 8]);
        v8h a1v = *reinterpret_cast<const v8h*>(&mbuf[wid][mt * 16 + arow][32 + kgrp * 8]);
        v4f c = {0.f, 0.f, 0.f, 0.f};
        c = __builtin_amdgcn_mfma_f32_16x16x32_f16(a0,  bf3a, c, 0, 0, 0);
        c = __builtin_amdgcn_mfma_f32_16x16x32_f16(a1v, bf3b, c, 0, 0, 0);
        if (arow < 3) {
            float4 st;
            st.x = tanhf(c[0] + bias3);
            st.y = tanhf(c[1] + bias3);
            st.z = tanhf(c[2] + bias3);
            st.w = tanhf(c[3] + bias3);
            size_t idx = ((size_t)b * 3 + arow) * N_PIX
                       + (size_t)(i0 + mt) * IMG + j0b + kgrp * 4;
            *reinterpret_cast<float4*>(&out[idx]) = st;
        }
    }
}

extern "C" void kernel_launch(void* const* d_in, const int* in_sizes, int n_in,
                              void* d_out, int out_size, void* d_ws, size_t ws_size,
                              hipStream_t stream)
{
    const float* z  = (const float*)d_in[0];
    const float* wt = (const float*)d_in[1];
    const float* bt = (const float*)d_in[2];
    const float* w1 = (const float*)d_in[3];
    const float* b1 = (const float*)d_in[4];
    const float* w2 = (const float*)d_in[5];
    const float* b2 = (const float*)d_in[6];
    const float* w3 = (const float*)d_in[7];
    const float* b3 = (const float*)d_in[8];
    float* out  = (float*)d_out;

    char* ws = (char*)d_ws;
    float*     tabs = (float*)ws;                            // 4 MB
    float*     part = (float*)(ws + (4 << 20));              // 16 MB partials
    _Float16*  w1T  = (_Float16*)(ws + (20 << 20));          // 4 KB
    _Float16*  w2T  = (_Float16*)(ws + (20 << 20) + 4096);   // 8 KB
    _Float16*  w3T  = (_Float16*)(ws + (20 << 20) + 12288);  // 2 KB
    float*     zT   = (float*)(ws + (20 << 20) + 16384);     // 16 KB

    ResArr ra;
    const double growth = std::exp((std::log(256.0) - std::log(16.0)) / 15.0);
    for (int l = 0; l < TABLE_NUM; ++l)
        ra.r[l] = (float)(16.0 * std::pow(growth, (double)l));

    prep_weights<<<16, 256, 0, stream>>>(w1, w2, w3, z, w1T, w2T, w3T, zT);
    gen_partial<<<KCHUNK * (NG4 / 256), 256, 0, stream>>>(zT, wt, part);
    gen_reduce<<<BATCH * NG4 / 256, 256, 0, stream>>>(part, bt, tabs);
    hash_mlp<<<BATCH * (N_PIX / 256), 256, 0, stream>>>(
        tabs, w1T, w2T, w3T, b1, b2, b3, out, ra);
}

// Round 17
// 90.813 us; speedup vs baseline: 1.0093x; 1.0093x over previous
//
#include <hip/hip_runtime.h>
#include <cmath>

#define TABLE_NUM 16
#define T_SIZE    4096
#define Z_DIM     512
#define IMG       256
#define D_TAB     (TABLE_NUM * T_SIZE * 2)       // 131072
#define BATCH     8
#define HID       64
#define N_PIX     (IMG * IMG)                    // 65536
#define PRIME_Y   2654435761u
#define KCHUNK    4
#define KLEN      (Z_DIM / KCHUNK)               // 128
#define NG4       (D_TAB / 4)                    // 32768 float4 col-groups

typedef _Float16 v8h  __attribute__((ext_vector_type(8)));
typedef _Float16 v2h  __attribute__((ext_vector_type(2)));
typedef float    v4f  __attribute__((ext_vector_type(4)));

struct ResArr { float r[TABLE_NUM]; };

// ---------------------------------------------------------------------------
// Kernel 0: weight transpose/cast + z transpose — grid-stride, 16 blocks.
// ---------------------------------------------------------------------------
__global__ void prep_weights(const float* __restrict__ w1, const float* __restrict__ w2,
                             const float* __restrict__ w3, const float* __restrict__ z,
                             _Float16* __restrict__ w1T, _Float16* __restrict__ w2T,
                             _Float16* __restrict__ w3T, float* __restrict__ zT)
{
    const int t0  = blockIdx.x * 256 + threadIdx.x;
    const int stp = gridDim.x * 256;
    for (int i = t0; i < HID * 32; i += stp) {
        int n = i >> 5, k = i & 31;
        w1T[i] = (_Float16)w1[k * HID + n];
    }
    for (int i = t0; i < HID * HID; i += stp) {
        int n = i >> 6, k = i & 63;
        w2T[i] = (_Float16)w2[k * HID + n];
    }
    for (int i = t0; i < 16 * HID; i += stp) {
        int n = i >> 6, k = i & 63;
        w3T[i] = (_Float16)(n < 3 ? w3[k * 3 + n] : 0.f);
    }
    for (int i = t0; i < Z_DIM * BATCH; i += stp) {
        int k = i >> 3, b = i & 7;
        zT[i] = z[b * Z_DIM + k];
    }
}

// ---------------------------------------------------------------------------
// Kernel 1a: k-split partial GEMM (unchanged from R7; ~44 us @ 6.4 TB/s).
// ---------------------------------------------------------------------------
__global__ __launch_bounds__(256) void gen_partial(
    const float* __restrict__ zT, const float* __restrict__ w,
    float* __restrict__ part)
{
    const int c  = blockIdx.x >> 7;
    const int g  = (blockIdx.x & 127) * 256 + threadIdx.x;
    const int k0 = c * KLEN;
    const float4* wp = reinterpret_cast<const float4*>(w) + g;

    float4 acc[BATCH];
#pragma unroll
    for (int b = 0; b < BATCH; ++b) acc[b] = make_float4(0.f, 0.f, 0.f, 0.f);

#pragma unroll 8
    for (int kk = 0; kk < KLEN; ++kk) {
        const int k = k0 + kk;
        float4 wv = wp[(size_t)k * NG4];
        const float* zr = zT + k * BATCH;
#pragma unroll
        for (int b = 0; b < BATCH; ++b) {
            float zv = zr[b];
            acc[b].x = fmaf(zv, wv.x, acc[b].x);
            acc[b].y = fmaf(zv, wv.y, acc[b].y);
            acc[b].z = fmaf(zv, wv.z, acc[b].z);
            acc[b].w = fmaf(zv, wv.w, acc[b].w);
        }
    }

    float4* pp = reinterpret_cast<float4*>(part);
#pragma unroll
    for (int b = 0; b < BATCH; ++b)
        pp[((size_t)(c * BATCH + b) << 15) + g] = acc[b];
}

// ---------------------------------------------------------------------------
// Kernel 1b: fold partials + bias (unchanged from R7; ~3.5 us).
// ---------------------------------------------------------------------------
__global__ __launch_bounds__(256) void gen_reduce(
    const float* __restrict__ part, const float* __restrict__ bt,
    float* __restrict__ tabs)
{
    const int i = blockIdx.x * 256 + threadIdx.x;
    const int b = i >> 15, g = i & (NG4 - 1);
    const float4* pp = reinterpret_cast<const float4*>(part);

    float4 s = pp[((size_t)b << 15) + g];
#pragma unroll
    for (int c = 1; c < KCHUNK; ++c) {
        float4 p = pp[((size_t)(c * BATCH + b) << 15) + g];
        s.x += p.x; s.y += p.y; s.z += p.z; s.w += p.w;
    }
    float4 bv = reinterpret_cast<const float4*>(bt)[g];
    s.x += bv.x; s.y += bv.y; s.z += bv.z; s.w += bv.w;
    reinterpret_cast<float4*>(tabs)[((size_t)b << 15) + g] = s;
}

// ---------------------------------------------------------------------------
// Kernel 2: R15 base (90.9 us, passing) + direct in-register layer-1 A:
// lane (arow,kgrp) computes levels 4*kgrp..4*kgrp+3 for pixels
// (i0+mt, j0+arow), mt=0..3 — exactly its a1[mt] MFMA fragment. Same 16
// bilerps/lane, same f32/f16 rounding points, but the feature->layer1 LDS
// round-trip (16 writes + drain + 4 b128 reads per lane) disappears and
// y-side hash math is shared 4x. res.r accessed via 4-way cndmask select
// (R10-proven; avoids runtime-indexed kernel-arg scratch). NO min-waves
// launch_bounds (convicted). mbuf first touched by layer-1 output.
// ---------------------------------------------------------------------------
__global__ __launch_bounds__(256) void hash_mlp(
    const float* __restrict__ tabs,
    const _Float16* __restrict__ w1T, const _Float16* __restrict__ w2T,
    const _Float16* __restrict__ w3T,
    const float* __restrict__ b1, const float* __restrict__ b2,
    const float* __restrict__ b3,
    float* __restrict__ out, ResArr res)
{
    __shared__ _Float16 mbuf[4][64][72];
    const int tid  = threadIdx.x;
    const int wid  = tid >> 6;
    const int lane = tid & 63;
    const int b    = blockIdx.x & 7;          // batch == XCD (round-robin)
    const int tile = blockIdx.x >> 3;         // 16x16 pixel block
    const int i0   = (tile >> 4) * 16 + wid * 4;
    const int j0   = (tile & 15) * 16;

    const int arow = lane & 15;        // A row / B col / C col
    const int kgrp = lane >> 4;        // k-group

    const float2* tb2 = reinterpret_cast<const float2*>(tabs + (size_t)b * D_TAB);

    // ---- features straight into a1 fragments (no LDS round-trip) ----
    const float cyp = ((float)(j0 + arow) + 0.5f) * (1.0f / IMG);
    v8h a1[4];
#pragma unroll
    for (int q = 0; q < 4; ++q) {
        const float r = (kgrp == 0) ? res.r[q]
                      : (kgrp == 1) ? res.r[4 + q]
                      : (kgrp == 2) ? res.r[8 + q]
                      :               res.r[12 + q];
        const float2* tl = tb2 + (kgrp * 4 + q) * T_SIZE;
        float py = cyp * r;
        float fy0 = floorf(py);
        float fy = py - fy0;
        unsigned y0 = (unsigned)(int)fy0;
        unsigned hy0 = y0 * PRIME_Y, hy1 = (y0 + 1u) * PRIME_Y;
#pragma unroll
        for (int mt = 0; mt < 4; ++mt) {
            const float cxp = ((float)(i0 + mt) + 0.5f) * (1.0f / IMG);
            float px = cxp * r;
            float fx0 = floorf(px);
            float fx = px - fx0;
            unsigned x0 = (unsigned)(int)fx0;
            unsigned i00 = (x0 ^ hy0) & (T_SIZE - 1);
            unsigned i10 = ((x0 + 1u) ^ hy0) & (T_SIZE - 1);
            unsigned i01 = (x0 ^ hy1) & (T_SIZE - 1);
            unsigned i11 = ((x0 + 1u) ^ hy1) & (T_SIZE - 1);
            float2 f00 = tl[i00], f10 = tl[i10], f01 = tl[i01], f11 = tl[i11];
            float w00 = (1.f - fx) * (1.f - fy);
            float w10 = fx * (1.f - fy);
            float w01 = (1.f - fx) * fy;
            float w11 = fx * fy;
            float e0 = f00.x * w00 + f10.x * w10 + f01.x * w01 + f11.x * w11;
            float e1 = f00.y * w00 + f10.y * w10 + f01.y * w01 + f11.y * w11;
            a1[mt][2 * q]     = (_Float16)e0;
            a1[mt][2 * q + 1] = (_Float16)e1;
        }
    }

    // ---- layer 1: 32 -> 64; per-nt fused relu+write (R15-verbatim) ----
#pragma unroll
    for (int nt = 0; nt < 4; ++nt) {
        v8h bf1 = *reinterpret_cast<const v8h*>(&w1T[(nt * 16 + arow) * 32 + kgrp * 8]);
        const float bias = b1[nt * 16 + arow];
#pragma unroll
        for (int mt = 0; mt < 4; ++mt) {
            v4f c = {0.f, 0.f, 0.f, 0.f};
            c = __builtin_amdgcn_mfma_f32_16x16x32_f16(a1[mt], bf1, c, 0, 0, 0);
#pragma unroll
            for (int e = 0; e < 4; ++e)
                mbuf[wid][mt * 16 + kgrp * 4 + e][nt * 16 + arow] =
                    (_Float16)fmaxf(c[e] + bias, 0.f);
        }
    }

    // ---- layer 2: 64 -> 64; a2 fully in regs first (WAR-safe) ----
    v8h a2[4][2];
#pragma unroll
    for (int mt = 0; mt < 4; ++mt) {
        a2[mt][0] = *reinterpret_cast<const v8h*>(&mbuf[wid][mt * 16 + arow][kgrp * 8]);
        a2[mt][1] = *reinterpret_cast<const v8h*>(&mbuf[wid][mt * 16 + arow][32 + kgrp * 8]);
    }
#pragma unroll
    for (int nt = 0; nt < 4; ++nt) {
        v8h bf2a = *reinterpret_cast<const v8h*>(&w2T[(nt * 16 + arow) * 64 + kgrp * 8]);
        v8h bf2b = *reinterpret_cast<const v8h*>(&w2T[(nt * 16 + arow) * 64 + 32 + kgrp * 8]);
        const float bias = b2[nt * 16 + arow];
#pragma unroll
        for (int mt = 0; mt < 4; ++mt) {
            v4f c = {0.f, 0.f, 0.f, 0.f};
            c = __builtin_amdgcn_mfma_f32_16x16x32_f16(a2[mt][0], bf2a, c, 0, 0, 0);
            c = __builtin_amdgcn_mfma_f32_16x16x32_f16(a2[mt][1], bf2b, c, 0, 0, 0);
#pragma unroll
            for (int e = 0; e < 4; ++e)
                mbuf[wid][mt * 16 + kgrp * 4 + e][nt * 16 + arow] =
                    (_Float16)fmaxf(c[e] + bias, 0.f);
        }
    }

    // ---- layer 3: 64 -> 3 (padded 16), tanh, coalesced row stores ----
    const float bias3 = (arow < 3) ? b3[arow] : 0.f;
#pragma unroll
    for (int mt = 0; mt < 4; ++mt) {
        v8h bf3a = *reinterpret_cast<const v8h*>(&w3T[arow * 64 + kgrp * 8]);
        v8h bf3b = *reinterpret_cast<const v8h*>(&w3T[arow * 64 + 32 + kgrp * 8]);
        v8h a0  = *reinterpret_cast<const v8h*>(&mbuf[wid][mt * 16 + arow][kgrp * 8]);
        v8h a1v = *reinterpret_cast<const v8h*>(&mbuf[wid][mt * 16 + arow][32 + kgrp * 8]);
        v4f c = {0.f, 0.f, 0.f, 0.f};
        c = __builtin_amdgcn_mfma_f32_16x16x32_f16(a0,  bf3a, c, 0, 0, 0);
        c = __builtin_amdgcn_mfma_f32_16x16x32_f16(a1v, bf3b, c, 0, 0, 0);
        if (arow < 3) {
            float4 st;
            st.x = tanhf(c[0] + bias3);
            st.y = tanhf(c[1] + bias3);
            st.z = tanhf(c[2] + bias3);
            st.w = tanhf(c[3] + bias3);
            size_t idx = ((size_t)b * 3 + arow) * N_PIX
                       + (size_t)(i0 + mt) * IMG + j0 + kgrp * 4;
            *reinterpret_cast<float4*>(&out[idx]) = st;
        }
    }
}

extern "C" void kernel_launch(void* const* d_in, const int* in_sizes, int n_in,
                              void* d_out, int out_size, void* d_ws, size_t ws_size,
                              hipStream_t stream)
{
    const float* z  = (const float*)d_in[0];
    const float* wt = (const float*)d_in[1];
    const float* bt = (const float*)d_in[2];
    const float* w1 = (const float*)d_in[3];
    const float* b1 = (const float*)d_in[4];
    const float* w2 = (const float*)d_in[5];
    const float* b2 = (const float*)d_in[6];
    const float* w3 = (const float*)d_in[7];
    const float* b3 = (const float*)d_in[8];
    float* out  = (float*)d_out;

    char* ws = (char*)d_ws;
    float*     tabs = (float*)ws;                            // 4 MB
    float*     part = (float*)(ws + (4 << 20));              // 16 MB partials
    _Float16*  w1T  = (_Float16*)(ws + (20 << 20));          // 4 KB
    _Float16*  w2T  = (_Float16*)(ws + (20 << 20) + 4096);   // 8 KB
    _Float16*  w3T  = (_Float16*)(ws + (20 << 20) + 12288);  // 2 KB
    float*     zT   = (float*)(ws + (20 << 20) + 16384);     // 16 KB

    ResArr ra;
    const double growth = std::exp((std::log(256.0) - std::log(16.0)) / 15.0);
    for (int l = 0; l < TABLE_NUM; ++l)
        ra.r[l] = (float)(16.0 * std::pow(growth, (double)l));

    prep_weights<<<16, 256, 0, stream>>>(w1, w2, w3, z, w1T, w2T, w3T, zT);
    gen_partial<<<KCHUNK * (NG4 / 256), 256, 0, stream>>>(zT, wt, part);
    gen_reduce<<<BATCH * NG4 / 256, 256, 0, stream>>>(part, bt, tabs);
    hash_mlp<<<BATCH * (N_PIX / 256), 256, 0, stream>>>(
        tabs, w1T, w2T, w3T, b1, b2, b3, out, ra);
}